// Round 2
// baseline (188.437 us; speedup 1.0000x reference)
//
#include <hip/hip_runtime.h>

// OHEM loss: exact k-th order statistic via 4-pass 8-bit radix select on a
// monotonic key, fused log-softmax NLL, masked mean.
//
// Kernels (7 launches):
//   init    : zero Ctrl
//   row     : read pred (256MB) coalesced 8-lanes/row -> keys, nll, hist[3], pos_num
//   hist2/1/0: redundant select-chain scan (LDS) + filtered histogram of next byte
//   reduce  : redundant select-chain -> full threshold key; masked sum/count
//   final   : loss = sum / max(cnt,1)

struct Ctrl {
    unsigned hist[4][256];   // histogram per radix pass (byte 3..0)
    unsigned pos_num;
    unsigned cnt;
    double   sum;
};

__global__ void init_kernel(unsigned* c, int words) {
    for (int i = threadIdx.x + blockIdx.x * blockDim.x; i < words;
         i += blockDim.x * gridDim.x)
        c[i] = 0u;
}

// Wave-aggregated LDS histogram add (top byte has few distinct values).
__device__ inline void wave_hist_add(unsigned* h, unsigned bucket) {
    unsigned long long todo = __ballot(1);
    while (todo) {
        int leader = (int)__builtin_ctzll(todo);
        unsigned b = __shfl(bucket, leader);
        unsigned long long same = __ballot(bucket == b) & todo;
        if ((int)(threadIdx.x & 63) == leader)
            atomicAdd(&h[b], (unsigned)__popcll(same));
        todo &= ~same;
    }
}

// 8 lanes per row: lane sub=0..7 holds cols 4*sub..4*sub+3 as one float4.
// Wave = 8 consecutive rows -> every global load is 1KB contiguous.
__global__ void __launch_bounds__(256)
row_kernel(const float4* __restrict__ pred4, const int* __restrict__ label,
           unsigned* __restrict__ keys, float* __restrict__ nll,
           Ctrl* __restrict__ c, int n) {
    __shared__ unsigned h[256];
    for (int i = threadIdx.x; i < 256; i += 256) h[i] = 0u;
    __syncthreads();

    const int lane  = threadIdx.x & 63;
    const int sub   = lane & 7;        // lane within 8-group (column chunk)
    const int gbase = lane & ~7;       // group's base lane in the wave

    int pos_local = 0;
    const int rows_per_iter = (gridDim.x * blockDim.x) >> 3;
    for (int row = (int)((blockIdx.x * blockDim.x + threadIdx.x) >> 3);
         row < n; row += rows_per_iter) {
        float4 v = pred4[(size_t)row * 8 + sub];

        // max over cols 1..31 (exclude background col 0, held by sub==0 .x)
        float m_nb = (sub == 0) ? fmaxf(fmaxf(v.y, v.z), v.w)
                                : fmaxf(fmaxf(v.x, v.y), fmaxf(v.z, v.w));
        m_nb = fmaxf(m_nb, __shfl_xor(m_nb, 1));
        m_nb = fmaxf(m_nb, __shfl_xor(m_nb, 2));
        m_nb = fmaxf(m_nb, __shfl_xor(m_nb, 4));
        float r0    = __shfl(v.x, gbase);          // col 0
        float m_all = fmaxf(m_nb, r0);

        float s = __expf(v.x - m_all) + __expf(v.y - m_all)
                + __expf(v.z - m_all) + __expf(v.w - m_all);
        s += __shfl_xor(s, 1);
        s += __shfl_xor(s, 2);
        s += __shfl_xor(s, 4);

        int lab = label[row];
        int sl = lab; sl = sl < 0 ? 0 : sl; sl = sl > 31 ? 31 : sl;
        float cand = (sl & 2) ? ((sl & 1) ? v.w : v.z)
                              : ((sl & 1) ? v.y : v.x);
        float xl = __shfl(cand, gbase | (sl >> 2));

        if (sub == 0) {
            nll[row] = (m_all + __logf(s)) - xl;
            bool is_pos = (lab != 0);
            pos_local += is_pos ? 1 : 0;
            float ns = is_pos ? -__builtin_inff() : m_nb;
            unsigned u    = __float_as_uint(ns);
            unsigned ukey = (u & 0x80000000u) ? ~u : (u | 0x80000000u);
            unsigned dkey = ~ukey;                 // ascending dkey = descending float
            keys[row] = dkey;
            wave_hist_add(h, dkey >> 24);
        }
    }

#pragma unroll
    for (int off = 32; off > 0; off >>= 1) pos_local += __shfl_down(pos_local, off);
    __shared__ int wsum[4];
    int wid = threadIdx.x >> 6;
    if ((threadIdx.x & 63) == 0) wsum[wid] = pos_local;
    __syncthreads();
    if (threadIdx.x == 0)
        atomicAdd(&c->pos_num, (unsigned)(wsum[0] + wsum[1] + wsum[2] + wsum[3]));

    for (int i = threadIdx.x; i < 256; i += 256)
        if (h[i]) atomicAdd(&c->hist[3][i], h[i]);
}

// Block-redundant radix select chain over completed histograms 3..upto_pass.
// Every block recomputes the same (prefix, rank, use_thr) -- removes the 4
// single-block scan kernel launches. Requires blockDim.x == 256.
__device__ void select_chain(const Ctrl* __restrict__ c, int n, int factor,
                             int upto_pass, unsigned& prefix_out,
                             unsigned& rank_out, bool& use_thr_out) {
    __shared__ unsigned s[256];
    __shared__ unsigned sh_byte, sh_rank;
    const int t = threadIdx.x;

    long long pos     = (long long)c->pos_num;
    long long neg_sum = pos * (long long)factor;
    long long num_neg = (long long)n - pos;
    long long idx     = neg_sum - 1;
    if (idx < 0) idx = 0;
    if (idx > (long long)n - 1) idx = (long long)n - 1;
    unsigned rank   = (unsigned)idx;
    unsigned prefix = 0u;

    for (int p = 3; p >= upto_pass; --p) {
        unsigned cnt = c->hist[p][t];
        __syncthreads();
        s[t] = cnt;
        __syncthreads();
#pragma unroll
        for (int off = 1; off < 256; off <<= 1) {
            unsigned v = (t >= off) ? s[t - off] : 0u;
            __syncthreads();
            s[t] += v;
            __syncthreads();
        }
        unsigned incl = s[t], excl = incl - cnt;
        if (cnt > 0u && excl <= rank && rank < incl) {
            sh_byte = (unsigned)t;
            sh_rank = rank - excl;
        }
        __syncthreads();
        prefix |= sh_byte << (8 * p);
        rank = sh_rank;
        __syncthreads();
    }
    prefix_out  = prefix;
    rank_out    = rank;
    use_thr_out = (num_neg > neg_sum);
}

__global__ void __launch_bounds__(256)
hist_kernel(const unsigned* __restrict__ keys, Ctrl* __restrict__ c,
            const int* __restrict__ factor_p, int n, int pass) {
    unsigned prefix, rank; bool use_thr;
    select_chain(c, n, factor_p[0], pass + 1, prefix, rank, use_thr);

    __shared__ unsigned h[256];
    for (int i = threadIdx.x; i < 256; i += 256) h[i] = 0u;
    __syncthreads();

    const unsigned pmask = 0xFFFFFFFFu << (8 * (pass + 1));
    const int shift = 8 * pass;
    const int stride = gridDim.x * blockDim.x;
    for (int i = blockIdx.x * blockDim.x + threadIdx.x; i < n; i += stride) {
        unsigned k = keys[i];
        if ((k & pmask) == prefix) atomicAdd(&h[(k >> shift) & 0xFFu], 1u);
    }
    __syncthreads();
    for (int i = threadIdx.x; i < 256; i += 256)
        if (h[i]) atomicAdd(&c->hist[pass][i], h[i]);
}

__global__ void __launch_bounds__(256)
reduce_kernel(const unsigned* __restrict__ keys, const int* __restrict__ label,
              const float* __restrict__ nll, Ctrl* __restrict__ c,
              const int* __restrict__ factor_p, int n) {
    unsigned thr, rank; bool use_thr;
    select_chain(c, n, factor_p[0], 0, thr, rank, use_thr);

    double local = 0.0;
    int cntl = 0;
    const int stride = gridDim.x * blockDim.x;
    for (int i = blockIdx.x * blockDim.x + threadIdx.x; i < n; i += stride) {
        int lab = label[i];
        bool mask = use_thr ? ((lab != 0) || (keys[i] <= thr)) : (lab != -1);
        if (mask) { local += (double)nll[i]; cntl++; }
    }
#pragma unroll
    for (int off = 32; off > 0; off >>= 1) {
        local += __shfl_down(local, off);
        cntl  += __shfl_down(cntl, off);
    }
    __shared__ double sd[4];
    __shared__ int    si[4];
    int wid = threadIdx.x >> 6;
    if ((threadIdx.x & 63) == 0) { sd[wid] = local; si[wid] = cntl; }
    __syncthreads();
    if (threadIdx.x == 0) {
        atomicAdd(&c->sum, sd[0] + sd[1] + sd[2] + sd[3]);
        atomicAdd(&c->cnt, (unsigned)(si[0] + si[1] + si[2] + si[3]));
    }
}

__global__ void final_kernel(const Ctrl* __restrict__ c, float* __restrict__ out) {
    if (threadIdx.x == 0 && blockIdx.x == 0) {
        unsigned ct = c->cnt;
        double denom = (ct == 0u) ? 1.0 : (double)ct;
        out[0] = (float)(c->sum / denom);
    }
}

extern "C" void kernel_launch(void* const* d_in, const int* in_sizes, int n_in,
                              void* d_out, int out_size, void* d_ws, size_t ws_size,
                              hipStream_t stream) {
    const float* pred = (const float*)d_in[0];
    const int* label  = (const int*)d_in[1];
    const int* factor = (const int*)d_in[2];
    int n = in_sizes[1];
    float* out = (float*)d_out;

    char* ws = (char*)d_ws;
    Ctrl* c = (Ctrl*)ws;
    unsigned* keys = (unsigned*)(ws + 8192);
    float* nll = (float*)(ws + 8192 + (size_t)n * sizeof(unsigned));

    init_kernel<<<1, 256, 0, stream>>>((unsigned*)c, (int)(sizeof(Ctrl) / 4));
    row_kernel<<<2048, 256, 0, stream>>>((const float4*)pred, label, keys, nll, c, n);
    hist_kernel<<<1024, 256, 0, stream>>>(keys, c, factor, n, 2);
    hist_kernel<<<1024, 256, 0, stream>>>(keys, c, factor, n, 1);
    hist_kernel<<<1024, 256, 0, stream>>>(keys, c, factor, n, 0);
    reduce_kernel<<<2048, 256, 0, stream>>>(keys, label, nll, c, factor, n);
    final_kernel<<<1, 64, 0, stream>>>(c, out);
}